// Round 10
// baseline (1138.394 us; speedup 1.0000x reference)
//
#include <hip/hip_runtime.h>
#include <hip/hip_bf16.h>

constexpr int S   = 4096;
constexpr int D   = 2048;
constexpr int H   = 16;
constexpr int KVH = 4;
constexpr int HD  = 128;

using short8 = __attribute__((ext_vector_type(8))) short;
using f32x4  = __attribute__((ext_vector_type(4))) float;
using f32x16 = __attribute__((ext_vector_type(16))) float;

__device__ inline ushort f2bf(float f) {
  union { float f; unsigned u; } x{f};
  unsigned r = x.u + 0x7FFFu + ((x.u >> 16) & 1u);
  return (ushort)(r >> 16);
}
__device__ inline float bf2f(ushort h) {
  union { unsigned u; float f; } x{(unsigned)h << 16};
  return x.f;
}
// RNE pack: two floats -> bf16x2
__device__ inline unsigned pkbf(float a, float b) {
  union { float f; unsigned u; } xa{a}, xb{b};
  unsigned ra = xa.u + 0x7FFFu + ((xa.u >> 16) & 1u);
  unsigned rb = xb.u + 0x7FFFu + ((xb.u >> 16) & 1u);
#if __has_builtin(__builtin_amdgcn_perm)
  return __builtin_amdgcn_perm(rb, ra, 0x07060302u);
#else
  return (rb & 0xFFFF0000u) | (ra >> 16);
#endif
}
// truncating pack (1 VALU op): for P values in [0,1] feeding PV; ~0.2% downward bias
__device__ inline unsigned pkbf_t(float a, float b) {
  union { float f; unsigned u; } xa{a}, xb{b};
#if __has_builtin(__builtin_amdgcn_perm)
  return __builtin_amdgcn_perm(xb.u, xa.u, 0x07060302u);
#else
  return (xb.u & 0xFFFF0000u) | (xa.u >> 16);
#endif
}
__device__ inline float fast_exp2(float x) {
#if __has_builtin(__builtin_amdgcn_exp2f)
  return __builtin_amdgcn_exp2f(x);
#else
  return exp2f(x);
#endif
}

// lane i<->i+32 half exchange, one VALU op for TWO outputs:
// x = {a_lo, b_lo}, y = {a_hi, b_hi}  (verified correct by R6/R7/R9 harness passes)
__device__ inline void swap_half(unsigned a, unsigned b, unsigned& x, unsigned& y) {
#if __has_builtin(__builtin_amdgcn_permlane32_swap)
  using uint2v = __attribute__((ext_vector_type(2))) unsigned;
  uint2v r = __builtin_amdgcn_permlane32_swap(a, b, false, false);
  x = r[0]; y = r[1];
#else
  unsigned bx = __shfl_xor(b, 32), ax = __shfl_xor(a, 32);
  int p = (threadIdx.x & 63) >> 5;
  x = p ? bx : a;
  y = p ? b : ax;
#endif
}

__device__ inline void async_copy16(const ushort* g, ushort* l) {
  __builtin_amdgcn_global_load_lds(
      (const __attribute__((address_space(1))) unsigned int*)g,
      (__attribute__((address_space(3))) unsigned int*)l, 16, 0, 0);
}

// ---------------------------------------------------------------------------
// Fused fp32->bf16 convert (dst segments contiguous in ws)
// ---------------------------------------------------------------------------
constexpr size_t N_HID = (size_t)S * D;
constexpr size_t N_WQ  = (size_t)(H * HD) * D;
constexpr size_t N_WKV = (size_t)(KVH * HD) * D;
constexpr size_t C1_ = N_HID;
constexpr size_t C2_ = C1_ + N_WQ;
constexpr size_t C3_ = C2_ + N_WKV;
constexpr size_t C4_ = C3_ + N_WKV;
constexpr size_t C5_ = C4_ + N_WQ;

__global__ void cvt_all_kernel(const float* __restrict__ hid, const float* __restrict__ wq,
                               const float* __restrict__ wk, const float* __restrict__ wv,
                               const float* __restrict__ wo, ushort* __restrict__ dst) {
  size_t i = (size_t)blockIdx.x * blockDim.x + threadIdx.x;
  size_t off = i * 4;
  if (off >= C5_) return;
  const float* src;
  if      (off < C1_) src = hid + off;
  else if (off < C2_) src = wq + (off - C1_);
  else if (off < C3_) src = wk + (off - C2_);
  else if (off < C4_) src = wv + (off - C3_);
  else                src = wo + (off - C4_);
  float4 f = *(const float4*)src;
  ushort4 o;
  o.x = f2bf(f.x); o.y = f2bf(f.y); o.z = f2bf(f.z); o.w = f2bf(f.w);
  *(ushort4*)&dst[off] = o;
}

// ---------------------------------------------------------------------------
// bf16 MFMA GEMM tile (NT), m97 recipe — SINGLE-buffered (R3/R0 form; R7
// proved explicit dbuf regresses this structure, matching learn_hip m99/m100).
// OUT_MODE: 0 fp32, 1 bf16, 2 bf16 transposed.
// ROPE (new, R10): apply rotary embedding on the fp32 accumulator in the
// epilogue. Valid because each 128-wide N-tile covers EXACTLY one head
// (Q: 2048 = 16x128, K: 512 = 4x128), so the rotation pair (d, d+64) lives in
// warp (wr,wc) <-> (wr,wc^1), same lane, same (i,j,r). Exchange goes through
// the now-idle As/Bs LDS (16KB = one i-round of all 4 warps' acc[i][*]),
// 4 uniform rounds x 2 barriers. Rotating the fp32 acc is slightly MORE
// precise than the old standalone rope kernel (which rotated rounded bf16).
// ---------------------------------------------------------------------------
template <int OUT_MODE, bool ROPE>
__device__ __forceinline__ void gemm_tile(const ushort* __restrict__ A,
                                          const ushort* __restrict__ Bt,
                                          void* __restrict__ Cv,
                                          int M, int N, int K, int bxi, int byi,
                                          ushort* As, ushort* Bs,
                                          const int* __restrict__ pos) {
  const int bm = byi * 128;
  const int bn = bxi * 128;
  const int tid  = threadIdx.x;
  const int lane = tid & 63;
  const int w    = tid >> 6;
  const int wr = w >> 1, wc = w & 1;
  const int lm = lane & 15, quad = lane >> 4;

  f32x4 acc[4][4];
#pragma unroll
  for (int i = 0; i < 4; ++i)
#pragma unroll
    for (int j = 0; j < 4; ++j) acc[i][j] = (f32x4){0.f, 0.f, 0.f, 0.f};

  for (int k0 = 0; k0 < K; k0 += 32) {
#pragma unroll
    for (int j = 0; j < 2; ++j) {
      int idx = j * 256 + tid;
      int row = idx >> 2;
      int col = (idx & 3) * 8;
      int ubase = (j * 256 + w * 64) * 8;
      async_copy16(A + (size_t)(bm + row) * K + k0 + col, &As[ubase]);
      async_copy16(Bt + (size_t)(bn + row) * K + k0 + col, &Bs[ubase]);
    }
    __syncthreads();
    short8 af[4], bfr[4];
#pragma unroll
    for (int t = 0; t < 4; ++t) {
      af[t]  = *(const short8*)&As[(wr * 64 + t * 16 + lm) * 32 + quad * 8];
      bfr[t] = *(const short8*)&Bs[(wc * 64 + t * 16 + lm) * 32 + quad * 8];
    }
#pragma unroll
    for (int i = 0; i < 4; ++i)
#pragma unroll
      for (int j = 0; j < 4; ++j)
        acc[i][j] = __builtin_amdgcn_mfma_f32_16x16x32_bf16(af[i], bfr[j], acc[i][j], 0, 0, 0);
    __syncthreads();
  }

  if (ROPE) {
    // ---- fused RoPE: exchange col^64 partner via LDS, rotate fp32 acc ----
    float* exA = (float*)As;   // 2048 floats (8KB)
    float* exB = (float*)Bs;   // 2048 floats (8KB)
#pragma unroll
    for (int i = 0; i < 4; ++i) {
      __syncthreads();         // prior round's reads (or K-loop) done
#pragma unroll
      for (int j = 0; j < 4; ++j) {
        float* ex = (j < 2) ? exA : exB;
        int base = ((w * 2 + (j & 1)) * 4) * 64;
#pragma unroll
        for (int r = 0; r < 4; ++r)
          ex[base + r * 64 + lane] = acc[i][j][r];
      }
      __syncthreads();
#pragma unroll
      for (int j = 0; j < 4; ++j) {
        const float* ex = (j < 2) ? exA : exB;
        int pbase = ((((w ^ 1) * 2) + (j & 1)) * 4) * 64;   // partner warp wc^1
        int j2 = j * 16 + lm;                               // d & 63
        float invf = exp2f(-(float)j2 * (13.287712379549449f / 64.0f));
#pragma unroll
        for (int r = 0; r < 4; ++r) {
          int srow = bm + wr * 64 + i * 16 + quad * 4 + r;
          float ang = (float)pos[srow] * invf;
          float c = cosf(ang), sn = sinf(ang);
          float part = ex[pbase + r * 64 + lane];
          float mine = acc[i][j][r];
          acc[i][j][r] = wc ? (mine * c + part * sn)        // d >= 64: x*c + x1*s
                            : (mine * c - part * sn);       // d < 64:  x*c - x2*s
        }
      }
    }
  }

#pragma unroll
  for (int i = 0; i < 4; ++i)
#pragma unroll
    for (int j = 0; j < 4; ++j) {
      if (OUT_MODE == 2) {
        int col  = bn + wc * 64 + j * 16 + lm;
        int rowb = bm + wr * 64 + i * 16 + quad * 4;
        ushort4 o4;
        o4.x = f2bf(acc[i][j][0]); o4.y = f2bf(acc[i][j][1]);
        o4.z = f2bf(acc[i][j][2]); o4.w = f2bf(acc[i][j][3]);
        *(ushort4*)&((ushort*)Cv)[(size_t)col * M + rowb] = o4;
      } else {
#pragma unroll
        for (int r = 0; r < 4; ++r) {
          size_t row = bm + wr * 64 + i * 16 + quad * 4 + r;
          size_t col = bn + wc * 64 + j * 16 + lm;
          if (OUT_MODE == 1) ((ushort*)Cv)[row * N + col] = f2bf(acc[i][j][r]);
          else               ((float*)Cv)[row * N + col]  = acc[i][j][r];
        }
      }
    }
}

__global__ __launch_bounds__(256) void gemm_qkv_kernel(const ushort* __restrict__ hb,
                                                       const ushort* __restrict__ wq,
                                                       const ushort* __restrict__ wk,
                                                       const ushort* __restrict__ wv,
                                                       ushort* __restrict__ qb,
                                                       ushort* __restrict__ kb,
                                                       ushort* __restrict__ vtb,
                                                       const int* __restrict__ pos) {
  __shared__ __align__(16) ushort As[128 * 32];
  __shared__ __align__(16) ushort Bs[128 * 32];
  int bid = blockIdx.x;
  if (bid < 512) {
    gemm_tile<1, true>(hb, wq, qb, S, H * HD, D, bid & 15, bid >> 4, As, Bs, pos);
  } else if (bid < 640) {
    int b = bid - 512;
    gemm_tile<1, true>(hb, wk, kb, S, KVH * HD, D, b & 3, b >> 2, As, Bs, pos);
  } else {
    int b = bid - 640;
    gemm_tile<2, false>(hb, wv, vtb, S, KVH * HD, D, b & 3, b >> 2, As, Bs, pos);
  }
}

template <int OUT_MODE>
__global__ __launch_bounds__(256) void gemm_bt_kernel(const ushort* __restrict__ A,
                                                      const ushort* __restrict__ Bt,
                                                      void* __restrict__ Cv,
                                                      int M, int N, int K) {
  __shared__ __align__(16) ushort As[128 * 32];
  __shared__ __align__(16) ushort Bs[128 * 32];
  gemm_tile<OUT_MODE, false>(A, Bt, Cv, M, N, K, blockIdx.x, blockIdx.y, As, Bs, nullptr);
}

// ---------------------------------------------------------------------------
// Transposed-flow bf16 MFMA causal flash attention (32x32x16), frag-major LDS.
// EXACT R9 attn kernel (114.6 us best-measured):
//  - kvh-per-XCD pinning (R3: FETCH 30.7 -> 16.4 MB)
//  - P lane^32 exchange via v_permlane32_swap (R7: -4.6 us vs ds_bpermute)
// [R6 lesson: V must stay LDS-staged; direct global V-frags = 64-line scatter.]
// Block = 512 thr = 8 waves = 4 q-groups x 2 kv-parities; q-tile 128; kv 64.
// Grid 512, descending qi; XCD = bid%8, h = 2*(bid&7)+((bid>>3)&1).
// ---------------------------------------------------------------------------
__global__ __launch_bounds__(512) void attn_mfma_kernel(const ushort* __restrict__ q,
                                                        const ushort* __restrict__ k,
                                                        const ushort* __restrict__ Vt,
                                                        ushort* __restrict__ o) {
  const int bid = blockIdx.x;
  const int h   = 2 * (bid & 7) + ((bid >> 3) & 1);   // kvh = h>>2 constant per XCD
  const int t   = bid >> 4;                 // 0..31
  const int qi  = 31 - t;                   // descending work order
  const int q0  = qi * 128;
  const int kvh = h >> 2;
  const int tid  = threadIdx.x;
  const int lane = tid & 63;
  const int w    = tid >> 6;                // 0..7
  const int qw   = w >> 1;                  // q-group 0..3
  const int ks   = w & 1;                   // kv parity 0..1
  const int m32  = lane & 31;
  const int p    = lane >> 5;

  // [buf][K: 16 chunks x 512] at 0 / [buf][V: 16 chunks x 512] at 16384
  __shared__ __align__(16) ushort LDSu[32768];

  const int q0w = q0 + qw * 32;

  // Q B-frags: B[n=q=lane&31][d=16s+8p+j]
  short8 qf[8];
#pragma unroll
  for (int s = 0; s < 8; ++s)
    qf[s] = *(const short8*)&q[(size_t)(q0w + m32) * (H * HD) + h * HD + s * 16 + p * 8];

  f32x16 Oacc[4];
#pragma unroll
  for (int i = 0; i < 4; ++i)
#pragma unroll
    for (int r = 0; r < 16; ++r) Oacc[i][r] = 0.f;
  float ls4[4] = {0.f, 0.f, 0.f, 0.f};      // 4 independent lsum chains

  // wave w stages chunks [4w, 4w+4): waves 0-3 -> K, waves 4-7 -> V
  auto stage = [&](int k0s, int buf) {
#pragma unroll
    for (int i = 0; i < 4; ++i) {
      int c = w * 4 + i;
      if (c < 16) {
        int kh = c >> 3, s = c & 7;
        async_copy16(&k[(size_t)(k0s + kh * 32 + m32) * (KVH * HD) + kvh * HD + s * 16 + p * 8],
                     &LDSu[buf * 8192 + c * 512]);
      } else {
        int cv = c - 16;
        int ht = cv >> 2, t2 = cv & 3;
        async_copy16(&Vt[(size_t)(kvh * HD + ht * 32 + m32) * S + k0s + t2 * 16 + p * 8],
                     &LDSu[16384 + buf * 8192 + cv * 512]);
      }
    }
  };

  stage(0, 0);
  __syncthreads();

  const float C1  = 0.08838834764831845f * 1.4426950408889634f;  // scale*log2e
  const float F2n = -12.0f * 1.4426950408889634f;                // -FM*log2e
  const int T = 2 * qi + 2;

  for (int tt = 0; tt < T; ++tt) {
    const int k0  = tt * 64;
    const int cur = tt & 1;
    if (tt + 1 < T) stage(k0 + 64, cur ^ 1);
    const ushort* Kb = &LDSu[cur * 8192];
    const ushort* Vb = &LDSu[16384 + cur * 8192];

    const int kbase = k0 + ks * 32;          // this wave's kv-subtile
    if (kbase <= q0w + 31) {                 // wave-uniform subtile liveness
      // ---- S^T subtile: 8 MFMA, two independent chains ----
      f32x16 stA, stB;
#pragma unroll
      for (int r = 0; r < 16; ++r) { stA[r] = 0.f; stB[r] = 0.f; }
#pragma unroll
      for (int s = 0; s < 8; s += 2) {
        short8 kf0 = *(const short8*)&Kb[(ks * 8 + s) * 512 + lane * 8];
        short8 kf1 = *(const short8*)&Kb[(ks * 8 + s + 1) * 512 + lane * 8];
        stA = __builtin_amdgcn_mfma_f32_32x32x16_bf16(kf0, qf[s], stA, 0, 0, 0);
        stB = __builtin_amdgcn_mfma_f32_32x32x16_bf16(kf1, qf[s + 1], stB, 0, 0, 0);
      }

      // ---- softmax terms ----
      float pv[16];
      if (kbase == q0w) {                    // diagonal subtile: masked path
#pragma unroll
        for (int r = 0; r < 16; ++r) {
          int kvl = (r & 3) + 8 * (r >> 2) + 4 * p;
          float e = fast_exp2(fmaf(stA[r] + stB[r], C1, F2n));
          e = (kvl > m32) ? 0.f : e;
          pv[r] = e; ls4[r & 3] += e;
        }
      } else {                               // clean subtile: no compares
#pragma unroll
        for (int r = 0; r < 16; ++r) {
          float e = fast_exp2(fmaf(stA[r] + stB[r], C1, F2n));
          pv[r] = e; ls4[r & 3] += e;
        }
      }

      // ---- C-layout -> PV B-frag: pack + permlane32_swap (VALU, no DS) ----
      unsigned own2[4][2];
#pragma unroll
      for (int g = 0; g < 4; ++g) {
        own2[g][0] = pkbf_t(pv[4 * g + 0], pv[4 * g + 1]);
        own2[g][1] = pkbf_t(pv[4 * g + 2], pv[4 * g + 3]);
      }
      short8 pf[2];
#pragma unroll
      for (int t2 = 0; t2 < 2; ++t2) {
        unsigned x0, y0, x1, y1;
        swap_half(own2[2 * t2][0], own2[2 * t2 + 1][0], x0, y0);
        swap_half(own2[2 * t2][1], own2[2 * t2 + 1][1], x1, y1);
        union { unsigned u4[4]; short8 s8; } pb;
        pb.u4[0] = x0; pb.u4[1] = x1; pb.u4[2] = y0; pb.u4[3] = y1;
        pf[t2] = pb.s8;
      }

      // ---- O^T += V^T·P : 8 MFMA (4 independent ht chains) ----
#pragma unroll
      for (int ht = 0; ht < 4; ++ht)
#pragma unroll
        for (int t2l = 0; t2l < 2; ++t2l) {
          int cv = ht * 4 + ks * 2 + t2l;
          short8 vf = *(const short8*)&Vb[cv * 512 + lane * 8];
          Oacc[ht] = __builtin_amdgcn_mfma_f32_32x32x16_bf16(vf, pf[t2l], Oacc[ht], 0, 0, 0);
        }
    }
    __syncthreads();
  }

  // ---- epilogue: merge kv-parity partners through LDS, then store ----
  float lsum = (ls4[0] + ls4[1]) + (ls4[2] + ls4[3]);
  float* mb = (float*)LDSu;                  // 16384 floats, loop is done with LDS

  // phase 1: lsum exchange (ks=1 -> ks=0)
  if (ks) mb[(qw << 6) | lane] = lsum;
  __syncthreads();
  if (!ks) lsum += mb[(qw << 6) | lane];
  __syncthreads();

  // phase 2: Oacc exchange, conflict-free [r][lane] layout (stride 4B)
  if (ks) {
    float* base = mb + qw * 4096;
#pragma unroll
    for (int ht = 0; ht < 4; ++ht)
#pragma unroll
      for (int r = 0; r < 16; ++r)
        base[ht * 1024 + r * 64 + lane] = Oacc[ht][r];
  }
  __syncthreads();

  if (!ks) {
    const float* base = mb + qw * 4096;
#pragma unroll
    for (int ht = 0; ht < 4; ++ht)
#pragma unroll
      for (int r = 0; r < 16; ++r)
        Oacc[ht][r] += base[ht * 1024 + r * 64 + lane];

    float ltot = lsum + __shfl_xor(lsum, 32);
    float inv = 1.0f / ltot;
#pragma unroll
    for (int ht = 0; ht < 4; ++ht)
#pragma unroll
      for (int rq = 0; rq < 4; ++rq) {
        uint2 dd;
        dd.x = pkbf(Oacc[ht][4 * rq + 0] * inv, Oacc[ht][4 * rq + 1] * inv);
        dd.y = pkbf(Oacc[ht][4 * rq + 2] * inv, Oacc[ht][4 * rq + 3] * inv);
        *(uint2*)&o[(size_t)(q0w + m32) * (H * HD) + h * HD + ht * 32 + 8 * rq + 4 * p] = dd;
      }
  }
}

// ---------------------------------------------------------------------------
// cvt(1) -> fused QKV proj + RoPE(1) -> flash attn(1) -> O proj(1)
// ---------------------------------------------------------------------------
extern "C" void kernel_launch(void* const* d_in, const int* in_sizes, int n_in,
                              void* d_out, int out_size, void* d_ws, size_t ws_size,
                              hipStream_t stream) {
  const float* hidden = (const float*)d_in[0];
  const float* Wq     = (const float*)d_in[1];
  const float* Wk     = (const float*)d_in[2];
  const float* Wv     = (const float*)d_in[3];
  const float* Wo     = (const float*)d_in[4];
  const int*   pos    = (const int*)d_in[5];
  float* out = (float*)d_out;

  ushort* hb  = (ushort*)d_ws;
  ushort* wqb = hb  + N_HID;
  ushort* wkb = wqb + N_WQ;
  ushort* wvb = wkb + N_WKV;
  ushort* wob = wvb + N_WKV;
  ushort* qb  = wob + N_WQ;
  ushort* kb  = qb  + (size_t)S * (H * HD);
  ushort* vtb = kb  + (size_t)S * (KVH * HD);
  ushort* ob  = vtb + (size_t)(KVH * HD) * S;

  dim3 blk(256);
  size_t n4 = C5_ / 4;
  cvt_all_kernel<<<(int)((n4 + 255) / 256), blk, 0, stream>>>(hidden, Wq, Wk, Wv, Wo, hb);

  gemm_qkv_kernel<<<dim3(768), blk, 0, stream>>>(hb, wqb, wkb, wvb, qb, kb, vtb, pos);

  attn_mfma_kernel<<<dim3(512), dim3(512), 0, stream>>>(qb, kb, vtb, ob);

  gemm_bt_kernel<0><<<dim3(D / 128, S / 128), blk, 0, stream>>>(ob, wob, out, S, D, D);
}

// Round 11
// 370.051 us; speedup vs baseline: 3.0763x; 3.0763x over previous
//
#include <hip/hip_runtime.h>
#include <hip/hip_bf16.h>

constexpr int S   = 4096;
constexpr int D   = 2048;
constexpr int H   = 16;
constexpr int KVH = 4;
constexpr int HD  = 128;

using short8 = __attribute__((ext_vector_type(8))) short;
using f32x4  = __attribute__((ext_vector_type(4))) float;
using f32x16 = __attribute__((ext_vector_type(16))) float;

__device__ inline ushort f2bf(float f) {
  union { float f; unsigned u; } x{f};
  unsigned r = x.u + 0x7FFFu + ((x.u >> 16) & 1u);
  return (ushort)(r >> 16);
}
__device__ inline float bf2f(ushort h) {
  union { unsigned u; float f; } x{(unsigned)h << 16};
  return x.f;
}
// RNE pack: two floats -> bf16x2
__device__ inline unsigned pkbf(float a, float b) {
  union { float f; unsigned u; } xa{a}, xb{b};
  unsigned ra = xa.u + 0x7FFFu + ((xa.u >> 16) & 1u);
  unsigned rb = xb.u + 0x7FFFu + ((xb.u >> 16) & 1u);
#if __has_builtin(__builtin_amdgcn_perm)
  return __builtin_amdgcn_perm(rb, ra, 0x07060302u);
#else
  return (rb & 0xFFFF0000u) | (ra >> 16);
#endif
}
// truncating pack (1 VALU op): for P values in [0,1] feeding PV; ~0.2% downward bias
__device__ inline unsigned pkbf_t(float a, float b) {
  union { float f; unsigned u; } xa{a}, xb{b};
#if __has_builtin(__builtin_amdgcn_perm)
  return __builtin_amdgcn_perm(xb.u, xa.u, 0x07060302u);
#else
  return (xb.u & 0xFFFF0000u) | (xa.u >> 16);
#endif
}
__device__ inline float fast_exp2(float x) {
#if __has_builtin(__builtin_amdgcn_exp2f)
  return __builtin_amdgcn_exp2f(x);
#else
  return exp2f(x);
#endif
}

// lane i<->i+32 half exchange, one VALU op for TWO outputs:
// x = {a_lo, b_lo}, y = {a_hi, b_hi}  (verified correct by R6/R7/R9 harness passes)
__device__ inline void swap_half(unsigned a, unsigned b, unsigned& x, unsigned& y) {
#if __has_builtin(__builtin_amdgcn_permlane32_swap)
  using uint2v = __attribute__((ext_vector_type(2))) unsigned;
  uint2v r = __builtin_amdgcn_permlane32_swap(a, b, false, false);
  x = r[0]; y = r[1];
#else
  unsigned bx = __shfl_xor(b, 32), ax = __shfl_xor(a, 32);
  int p = (threadIdx.x & 63) >> 5;
  x = p ? bx : a;
  y = p ? b : ax;
#endif
}

__device__ inline void async_copy16(const ushort* g, ushort* l) {
  __builtin_amdgcn_global_load_lds(
      (const __attribute__((address_space(1))) unsigned int*)g,
      (__attribute__((address_space(3))) unsigned int*)l, 16, 0, 0);
}

// ---------------------------------------------------------------------------
// Fused fp32->bf16 convert (dst segments contiguous in ws)
// ---------------------------------------------------------------------------
constexpr size_t N_HID = (size_t)S * D;
constexpr size_t N_WQ  = (size_t)(H * HD) * D;
constexpr size_t N_WKV = (size_t)(KVH * HD) * D;
constexpr size_t C1_ = N_HID;
constexpr size_t C2_ = C1_ + N_WQ;
constexpr size_t C3_ = C2_ + N_WKV;
constexpr size_t C4_ = C3_ + N_WKV;
constexpr size_t C5_ = C4_ + N_WQ;

__global__ void cvt_all_kernel(const float* __restrict__ hid, const float* __restrict__ wq,
                               const float* __restrict__ wk, const float* __restrict__ wv,
                               const float* __restrict__ wo, ushort* __restrict__ dst) {
  size_t i = (size_t)blockIdx.x * blockDim.x + threadIdx.x;
  size_t off = i * 4;
  if (off >= C5_) return;
  const float* src;
  if      (off < C1_) src = hid + off;
  else if (off < C2_) src = wq + (off - C1_);
  else if (off < C3_) src = wk + (off - C2_);
  else if (off < C4_) src = wv + (off - C3_);
  else                src = wo + (off - C4_);
  float4 f = *(const float4*)src;
  ushort4 o;
  o.x = f2bf(f.x); o.y = f2bf(f.y); o.z = f2bf(f.z); o.w = f2bf(f.w);
  *(ushort4*)&dst[off] = o;
}

// ---------------------------------------------------------------------------
// RoPE cos/sin table: tab[s*64 + j2] = {cos, sin}(pos[s] * invf(j2)). 2MB,
// L2-resident. Removes ALL libm from the GEMM epilogue (R10 lesson: 64 hoisted
// sinf/cosf in the unrolled epilogue spilled acc across the K-loop -> 2.7GB
// scratch writes, 10x regression).
// ---------------------------------------------------------------------------
__global__ void trig_table_kernel(const int* __restrict__ pos, float2* __restrict__ tab) {
  int idx = blockIdx.x * 256 + threadIdx.x;
  if (idx >= S * 64) return;
  int s = idx >> 6, j2 = idx & 63;
  float invf = exp2f(-(float)j2 * (13.287712379549449f / 64.0f));
  float ang = (float)pos[s] * invf;
  float2 cs; cs.x = cosf(ang); cs.y = sinf(ang);
  tab[idx] = cs;
}

// ---------------------------------------------------------------------------
// bf16 MFMA GEMM tile (NT), m97 recipe — SINGLE-buffered (R3/R0 form; R7
// proved explicit dbuf regresses this structure, matching learn_hip m99/m100).
// OUT_MODE: 0 fp32, 1 bf16, 2 bf16 transposed.
// ROPE (R10 math verified correct; R11 spill-fixed): rotation applied on the
// fp32 accumulator in the epilogue. Each 128-wide N-tile covers EXACTLY one
// head, so the pair (d, d+64) lives in warp (wr,wc) <-> (wr,wc^1), same lane,
// same (i,j,r); exchanged through the idle As/Bs LDS in 4 uniform rounds.
// cos/sin come from the precomputed table (no libm), and the C-store is
// folded into each round so acc[i] dies at round i -> epilogue peak pressure
// stays below the K-loop's allocation (no acc spill).
// ---------------------------------------------------------------------------
template <int OUT_MODE, bool ROPE>
__device__ __forceinline__ void gemm_tile(const ushort* __restrict__ A,
                                          const ushort* __restrict__ Bt,
                                          void* __restrict__ Cv,
                                          int M, int N, int K, int bxi, int byi,
                                          ushort* As, ushort* Bs,
                                          const float2* __restrict__ tab) {
  const int bm = byi * 128;
  const int bn = bxi * 128;
  const int tid  = threadIdx.x;
  const int lane = tid & 63;
  const int w    = tid >> 6;
  const int wr = w >> 1, wc = w & 1;
  const int lm = lane & 15, quad = lane >> 4;

  f32x4 acc[4][4];
#pragma unroll
  for (int i = 0; i < 4; ++i)
#pragma unroll
    for (int j = 0; j < 4; ++j) acc[i][j] = (f32x4){0.f, 0.f, 0.f, 0.f};

  for (int k0 = 0; k0 < K; k0 += 32) {
#pragma unroll
    for (int j = 0; j < 2; ++j) {
      int idx = j * 256 + tid;
      int row = idx >> 2;
      int col = (idx & 3) * 8;
      int ubase = (j * 256 + w * 64) * 8;
      async_copy16(A + (size_t)(bm + row) * K + k0 + col, &As[ubase]);
      async_copy16(Bt + (size_t)(bn + row) * K + k0 + col, &Bs[ubase]);
    }
    __syncthreads();
    short8 af[4], bfr[4];
#pragma unroll
    for (int t = 0; t < 4; ++t) {
      af[t]  = *(const short8*)&As[(wr * 64 + t * 16 + lm) * 32 + quad * 8];
      bfr[t] = *(const short8*)&Bs[(wc * 64 + t * 16 + lm) * 32 + quad * 8];
    }
#pragma unroll
    for (int i = 0; i < 4; ++i)
#pragma unroll
      for (int j = 0; j < 4; ++j)
        acc[i][j] = __builtin_amdgcn_mfma_f32_16x16x32_bf16(af[i], bfr[j], acc[i][j], 0, 0, 0);
    __syncthreads();
  }

  if (ROPE) {
    // ---- fused RoPE (table-driven) + store, per i-round ----
    float* exA = (float*)As;   // 2048 floats (8KB)
    float* exB = (float*)Bs;   // 2048 floats (8KB)
#pragma unroll
    for (int i = 0; i < 4; ++i) {
      __syncthreads();         // prior round's reads (or K-loop) done
#pragma unroll
      for (int j = 0; j < 4; ++j) {
        float* ex = (j < 2) ? exA : exB;
        int base = (w * 2 + (j & 1)) * 256;
#pragma unroll
        for (int r = 0; r < 4; ++r)
          ex[base + r * 64 + lane] = acc[i][j][r];
      }
      __syncthreads();
#pragma unroll
      for (int j = 0; j < 4; ++j) {
        const float* ex = (j < 2) ? exA : exB;
        int pbase = ((w ^ 1) * 2 + (j & 1)) * 256;          // partner warp wc^1
        int j2 = j * 16 + lm;                               // d & 63
        int col = bn + wc * 64 + j * 16 + lm;
#pragma unroll
        for (int r = 0; r < 4; ++r) {
          int srow = bm + wr * 64 + i * 16 + quad * 4 + r;
          float2 cs = tab[(size_t)srow * 64 + j2];
          float part = ex[pbase + r * 64 + lane];
          float mine = acc[i][j][r];
          float v = wc ? fmaf(mine, cs.x, part * cs.y)      // d >= 64: x*c + x1*s
                       : fmaf(mine, cs.x, -(part * cs.y));  // d < 64:  x*c - x2*s
          ((ushort*)Cv)[(size_t)srow * N + col] = f2bf(v);
        }
      }
    }
    return;
  }

#pragma unroll
  for (int i = 0; i < 4; ++i)
#pragma unroll
    for (int j = 0; j < 4; ++j) {
      if (OUT_MODE == 2) {
        int col  = bn + wc * 64 + j * 16 + lm;
        int rowb = bm + wr * 64 + i * 16 + quad * 4;
        ushort4 o4;
        o4.x = f2bf(acc[i][j][0]); o4.y = f2bf(acc[i][j][1]);
        o4.z = f2bf(acc[i][j][2]); o4.w = f2bf(acc[i][j][3]);
        *(ushort4*)&((ushort*)Cv)[(size_t)col * M + rowb] = o4;
      } else {
#pragma unroll
        for (int r = 0; r < 4; ++r) {
          size_t row = bm + wr * 64 + i * 16 + quad * 4 + r;
          size_t col = bn + wc * 64 + j * 16 + lm;
          if (OUT_MODE == 1) ((ushort*)Cv)[row * N + col] = f2bf(acc[i][j][r]);
          else               ((float*)Cv)[row * N + col]  = acc[i][j][r];
        }
      }
    }
}

__global__ __launch_bounds__(256) void gemm_qkv_kernel(const ushort* __restrict__ hb,
                                                       const ushort* __restrict__ wq,
                                                       const ushort* __restrict__ wk,
                                                       const ushort* __restrict__ wv,
                                                       ushort* __restrict__ qb,
                                                       ushort* __restrict__ kb,
                                                       ushort* __restrict__ vtb,
                                                       const float2* __restrict__ tab) {
  __shared__ __align__(16) ushort As[128 * 32];
  __shared__ __align__(16) ushort Bs[128 * 32];
  int bid = blockIdx.x;
  if (bid < 512) {
    gemm_tile<1, true>(hb, wq, qb, S, H * HD, D, bid & 15, bid >> 4, As, Bs, tab);
  } else if (bid < 640) {
    int b = bid - 512;
    gemm_tile<1, true>(hb, wk, kb, S, KVH * HD, D, b & 3, b >> 2, As, Bs, tab);
  } else {
    int b = bid - 640;
    gemm_tile<2, false>(hb, wv, vtb, S, KVH * HD, D, b & 3, b >> 2, As, Bs, nullptr);
  }
}

template <int OUT_MODE>
__global__ __launch_bounds__(256) void gemm_bt_kernel(const ushort* __restrict__ A,
                                                      const ushort* __restrict__ Bt,
                                                      void* __restrict__ Cv,
                                                      int M, int N, int K) {
  __shared__ __align__(16) ushort As[128 * 32];
  __shared__ __align__(16) ushort Bs[128 * 32];
  gemm_tile<OUT_MODE, false>(A, Bt, Cv, M, N, K, blockIdx.x, blockIdx.y, As, Bs, nullptr);
}

// ---------------------------------------------------------------------------
// Transposed-flow bf16 MFMA causal flash attention (32x32x16), frag-major LDS.
// EXACT R9 attn kernel (114.6 us best-measured):
//  - kvh-per-XCD pinning (R3: FETCH 30.7 -> 16.4 MB)
//  - P lane^32 exchange via v_permlane32_swap (R7: -4.6 us vs ds_bpermute)
// [R6 lesson: V must stay LDS-staged; direct global V-frags = 64-line scatter.]
// Block = 512 thr = 8 waves = 4 q-groups x 2 kv-parities; q-tile 128; kv 64.
// Grid 512, descending qi; XCD = bid%8, h = 2*(bid&7)+((bid>>3)&1).
// ---------------------------------------------------------------------------
__global__ __launch_bounds__(512) void attn_mfma_kernel(const ushort* __restrict__ q,
                                                        const ushort* __restrict__ k,
                                                        const ushort* __restrict__ Vt,
                                                        ushort* __restrict__ o) {
  const int bid = blockIdx.x;
  const int h   = 2 * (bid & 7) + ((bid >> 3) & 1);   // kvh = h>>2 constant per XCD
  const int t   = bid >> 4;                 // 0..31
  const int qi  = 31 - t;                   // descending work order
  const int q0  = qi * 128;
  const int kvh = h >> 2;
  const int tid  = threadIdx.x;
  const int lane = tid & 63;
  const int w    = tid >> 6;                // 0..7
  const int qw   = w >> 1;                  // q-group 0..3
  const int ks   = w & 1;                   // kv parity 0..1
  const int m32  = lane & 31;
  const int p    = lane >> 5;

  // [buf][K: 16 chunks x 512] at 0 / [buf][V: 16 chunks x 512] at 16384
  __shared__ __align__(16) ushort LDSu[32768];

  const int q0w = q0 + qw * 32;

  // Q B-frags: B[n=q=lane&31][d=16s+8p+j]
  short8 qf[8];
#pragma unroll
  for (int s = 0; s < 8; ++s)
    qf[s] = *(const short8*)&q[(size_t)(q0w + m32) * (H * HD) + h * HD + s * 16 + p * 8];

  f32x16 Oacc[4];
#pragma unroll
  for (int i = 0; i < 4; ++i)
#pragma unroll
    for (int r = 0; r < 16; ++r) Oacc[i][r] = 0.f;
  float ls4[4] = {0.f, 0.f, 0.f, 0.f};      // 4 independent lsum chains

  // wave w stages chunks [4w, 4w+4): waves 0-3 -> K, waves 4-7 -> V
  auto stage = [&](int k0s, int buf) {
#pragma unroll
    for (int i = 0; i < 4; ++i) {
      int c = w * 4 + i;
      if (c < 16) {
        int kh = c >> 3, s = c & 7;
        async_copy16(&k[(size_t)(k0s + kh * 32 + m32) * (KVH * HD) + kvh * HD + s * 16 + p * 8],
                     &LDSu[buf * 8192 + c * 512]);
      } else {
        int cv = c - 16;
        int ht = cv >> 2, t2 = cv & 3;
        async_copy16(&Vt[(size_t)(kvh * HD + ht * 32 + m32) * S + k0s + t2 * 16 + p * 8],
                     &LDSu[16384 + buf * 8192 + cv * 512]);
      }
    }
  };

  stage(0, 0);
  __syncthreads();

  const float C1  = 0.08838834764831845f * 1.4426950408889634f;  // scale*log2e
  const float F2n = -12.0f * 1.4426950408889634f;                // -FM*log2e
  const int T = 2 * qi + 2;

  for (int tt = 0; tt < T; ++tt) {
    const int k0  = tt * 64;
    const int cur = tt & 1;
    if (tt + 1 < T) stage(k0 + 64, cur ^ 1);
    const ushort* Kb = &LDSu[cur * 8192];
    const ushort* Vb = &LDSu[16384 + cur * 8192];

    const int kbase = k0 + ks * 32;          // this wave's kv-subtile
    if (kbase <= q0w + 31) {                 // wave-uniform subtile liveness
      // ---- S^T subtile: 8 MFMA, two independent chains ----
      f32x16 stA, stB;
#pragma unroll
      for (int r = 0; r < 16; ++r) { stA[r] = 0.f; stB[r] = 0.f; }
#pragma unroll
      for (int s = 0; s < 8; s += 2) {
        short8 kf0 = *(const short8*)&Kb[(ks * 8 + s) * 512 + lane * 8];
        short8 kf1 = *(const short8*)&Kb[(ks * 8 + s + 1) * 512 + lane * 8];
        stA = __builtin_amdgcn_mfma_f32_32x32x16_bf16(kf0, qf[s], stA, 0, 0, 0);
        stB = __builtin_amdgcn_mfma_f32_32x32x16_bf16(kf1, qf[s + 1], stB, 0, 0, 0);
      }

      // ---- softmax terms ----
      float pv[16];
      if (kbase == q0w) {                    // diagonal subtile: masked path
#pragma unroll
        for (int r = 0; r < 16; ++r) {
          int kvl = (r & 3) + 8 * (r >> 2) + 4 * p;
          float e = fast_exp2(fmaf(stA[r] + stB[r], C1, F2n));
          e = (kvl > m32) ? 0.f : e;
          pv[r] = e; ls4[r & 3] += e;
        }
      } else {                               // clean subtile: no compares
#pragma unroll
        for (int r = 0; r < 16; ++r) {
          float e = fast_exp2(fmaf(stA[r] + stB[r], C1, F2n));
          pv[r] = e; ls4[r & 3] += e;
        }
      }

      // ---- C-layout -> PV B-frag: pack + permlane32_swap (VALU, no DS) ----
      unsigned own2[4][2];
#pragma unroll
      for (int g = 0; g < 4; ++g) {
        own2[g][0] = pkbf_t(pv[4 * g + 0], pv[4 * g + 1]);
        own2[g][1] = pkbf_t(pv[4 * g + 2], pv[4 * g + 3]);
      }
      short8 pf[2];
#pragma unroll
      for (int t2 = 0; t2 < 2; ++t2) {
        unsigned x0, y0, x1, y1;
        swap_half(own2[2 * t2][0], own2[2 * t2 + 1][0], x0, y0);
        swap_half(own2[2 * t2][1], own2[2 * t2 + 1][1], x1, y1);
        union { unsigned u4[4]; short8 s8; } pb;
        pb.u4[0] = x0; pb.u4[1] = x1; pb.u4[2] = y0; pb.u4[3] = y1;
        pf[t2] = pb.s8;
      }

      // ---- O^T += V^T·P : 8 MFMA (4 independent ht chains) ----
#pragma unroll
      for (int ht = 0; ht < 4; ++ht)
#pragma unroll
        for (int t2l = 0; t2l < 2; ++t2l) {
          int cv = ht * 4 + ks * 2 + t2l;
          short8 vf = *(const short8*)&Vb[cv * 512 + lane * 8];
          Oacc[ht] = __builtin_amdgcn_mfma_f32_32x32x16_bf16(vf, pf[t2l], Oacc[ht], 0, 0, 0);
        }
    }
    __syncthreads();
  }

  // ---- epilogue: merge kv-parity partners through LDS, then store ----
  float lsum = (ls4[0] + ls4[1]) + (ls4[2] + ls4[3]);
  float* mb = (float*)LDSu;                  // 16384 floats, loop is done with LDS

  // phase 1: lsum exchange (ks=1 -> ks=0)
  if (ks) mb[(qw << 6) | lane] = lsum;
  __syncthreads();
  if (!ks) lsum += mb[(qw << 6) | lane];
  __syncthreads();

  // phase 2: Oacc exchange, conflict-free [r][lane] layout (stride 4B)
  if (ks) {
    float* base = mb + qw * 4096;
#pragma unroll
    for (int ht = 0; ht < 4; ++ht)
#pragma unroll
      for (int r = 0; r < 16; ++r)
        base[ht * 1024 + r * 64 + lane] = Oacc[ht][r];
  }
  __syncthreads();

  if (!ks) {
    const float* base = mb + qw * 4096;
#pragma unroll
    for (int ht = 0; ht < 4; ++ht)
#pragma unroll
      for (int r = 0; r < 16; ++r)
        Oacc[ht][r] += base[ht * 1024 + r * 64 + lane];

    float ltot = lsum + __shfl_xor(lsum, 32);
    float inv = 1.0f / ltot;
#pragma unroll
    for (int ht = 0; ht < 4; ++ht)
#pragma unroll
      for (int rq = 0; rq < 4; ++rq) {
        uint2 dd;
        dd.x = pkbf(Oacc[ht][4 * rq + 0] * inv, Oacc[ht][4 * rq + 1] * inv);
        dd.y = pkbf(Oacc[ht][4 * rq + 2] * inv, Oacc[ht][4 * rq + 3] * inv);
        *(uint2*)&o[(size_t)(q0w + m32) * (H * HD) + h * HD + ht * 32 + 8 * rq + 4 * p] = dd;
      }
  }
}

// ---------------------------------------------------------------------------
// cvt(1) -> trig table(1) -> fused QKV proj + RoPE(1) -> flash attn(1)
// -> O proj(1)
// ---------------------------------------------------------------------------
extern "C" void kernel_launch(void* const* d_in, const int* in_sizes, int n_in,
                              void* d_out, int out_size, void* d_ws, size_t ws_size,
                              hipStream_t stream) {
  const float* hidden = (const float*)d_in[0];
  const float* Wq     = (const float*)d_in[1];
  const float* Wk     = (const float*)d_in[2];
  const float* Wv     = (const float*)d_in[3];
  const float* Wo     = (const float*)d_in[4];
  const int*   pos    = (const int*)d_in[5];
  float* out = (float*)d_out;

  ushort* hb  = (ushort*)d_ws;
  ushort* wqb = hb  + N_HID;
  ushort* wkb = wqb + N_WQ;
  ushort* wvb = wkb + N_WKV;
  ushort* wob = wvb + N_WKV;
  ushort* qb  = wob + N_WQ;
  ushort* kb  = qb  + (size_t)S * (H * HD);
  ushort* vtb = kb  + (size_t)S * (KVH * HD);
  ushort* ob  = vtb + (size_t)(KVH * HD) * S;
  float2* tab = (float2*)(ob + (size_t)S * (H * HD));   // 2MB (ws headroom proven in R5)

  dim3 blk(256);
  size_t n4 = C5_ / 4;
  cvt_all_kernel<<<(int)((n4 + 255) / 256), blk, 0, stream>>>(hidden, Wq, Wk, Wv, Wo, hb);

  trig_table_kernel<<<(S * 64 + 255) / 256, blk, 0, stream>>>(pos, tab);

  gemm_qkv_kernel<<<dim3(768), blk, 0, stream>>>(hb, wqb, wkb, wvb, qb, kb, vtb, tab);

  attn_mfma_kernel<<<dim3(512), dim3(512), 0, stream>>>(qb, kb, vtb, ob);

  gemm_bt_kernel<0><<<dim3(D / 128, S / 128), blk, 0, stream>>>(ob, wob, out, S, D, D);
}

// Round 12
// 345.890 us; speedup vs baseline: 3.2912x; 1.0699x over previous
//
#include <hip/hip_runtime.h>
#include <hip/hip_bf16.h>

constexpr int S   = 4096;
constexpr int D   = 2048;
constexpr int H   = 16;
constexpr int KVH = 4;
constexpr int HD  = 128;

using short8 = __attribute__((ext_vector_type(8))) short;
using f32x4  = __attribute__((ext_vector_type(4))) float;
using f32x16 = __attribute__((ext_vector_type(16))) float;

__device__ inline ushort f2bf(float f) {
  union { float f; unsigned u; } x{f};
  unsigned r = x.u + 0x7FFFu + ((x.u >> 16) & 1u);
  return (ushort)(r >> 16);
}
__device__ inline float bf2f(ushort h) {
  union { unsigned u; float f; } x{(unsigned)h << 16};
  return x.f;
}
// RNE pack: two floats -> bf16x2
__device__ inline unsigned pkbf(float a, float b) {
  union { float f; unsigned u; } xa{a}, xb{b};
  unsigned ra = xa.u + 0x7FFFu + ((xa.u >> 16) & 1u);
  unsigned rb = xb.u + 0x7FFFu + ((xb.u >> 16) & 1u);
#if __has_builtin(__builtin_amdgcn_perm)
  return __builtin_amdgcn_perm(rb, ra, 0x07060302u);
#else
  return (rb & 0xFFFF0000u) | (ra >> 16);
#endif
}
// truncating pack (1 VALU op): for P values in [0,1] feeding PV; ~0.2% downward bias
__device__ inline unsigned pkbf_t(float a, float b) {
  union { float f; unsigned u; } xa{a}, xb{b};
#if __has_builtin(__builtin_amdgcn_perm)
  return __builtin_amdgcn_perm(xb.u, xa.u, 0x07060302u);
#else
  return (xb.u & 0xFFFF0000u) | (xa.u >> 16);
#endif
}
__device__ inline float fast_exp2(float x) {
#if __has_builtin(__builtin_amdgcn_exp2f)
  return __builtin_amdgcn_exp2f(x);
#else
  return exp2f(x);
#endif
}

// lane i<->i+32 half exchange, one VALU op for TWO outputs:
// x = {a_lo, b_lo}, y = {a_hi, b_hi}  (verified correct by R6/R7/R9 harness passes)
__device__ inline void swap_half(unsigned a, unsigned b, unsigned& x, unsigned& y) {
#if __has_builtin(__builtin_amdgcn_permlane32_swap)
  using uint2v = __attribute__((ext_vector_type(2))) unsigned;
  uint2v r = __builtin_amdgcn_permlane32_swap(a, b, false, false);
  x = r[0]; y = r[1];
#else
  unsigned bx = __shfl_xor(b, 32), ax = __shfl_xor(a, 32);
  int p = (threadIdx.x & 63) >> 5;
  x = p ? bx : a;
  y = p ? b : ax;
#endif
}

__device__ inline void async_copy16(const ushort* g, ushort* l) {
  __builtin_amdgcn_global_load_lds(
      (const __attribute__((address_space(1))) unsigned int*)g,
      (__attribute__((address_space(3))) unsigned int*)l, 16, 0, 0);
}

// ---------------------------------------------------------------------------
// Fused fp32->bf16 convert (dst segments contiguous in ws)
// ---------------------------------------------------------------------------
constexpr size_t N_HID = (size_t)S * D;
constexpr size_t N_WQ  = (size_t)(H * HD) * D;
constexpr size_t N_WKV = (size_t)(KVH * HD) * D;
constexpr size_t C1_ = N_HID;
constexpr size_t C2_ = C1_ + N_WQ;
constexpr size_t C3_ = C2_ + N_WKV;
constexpr size_t C4_ = C3_ + N_WKV;
constexpr size_t C5_ = C4_ + N_WQ;

__global__ void cvt_all_kernel(const float* __restrict__ hid, const float* __restrict__ wq,
                               const float* __restrict__ wk, const float* __restrict__ wv,
                               const float* __restrict__ wo, ushort* __restrict__ dst) {
  size_t i = (size_t)blockIdx.x * blockDim.x + threadIdx.x;
  size_t off = i * 4;
  if (off >= C5_) return;
  const float* src;
  if      (off < C1_) src = hid + off;
  else if (off < C2_) src = wq + (off - C1_);
  else if (off < C3_) src = wk + (off - C2_);
  else if (off < C4_) src = wv + (off - C3_);
  else                src = wo + (off - C4_);
  float4 f = *(const float4*)src;
  ushort4 o;
  o.x = f2bf(f.x); o.y = f2bf(f.y); o.z = f2bf(f.z); o.w = f2bf(f.w);
  *(ushort4*)&dst[off] = o;
}

// ---------------------------------------------------------------------------
// RoPE cos/sin table: tab[s*64 + j2] = {cos, sin}(pos[s] * invf(j2)). 2MB,
// L2-resident. (R11-proven correct; removes libm from consumers.)
// ---------------------------------------------------------------------------
__global__ void trig_table_kernel(const int* __restrict__ pos, float2* __restrict__ tab) {
  int idx = blockIdx.x * 256 + threadIdx.x;
  if (idx >= S * 64) return;
  int s = idx >> 6, j2 = idx & 63;
  float invf = exp2f(-(float)j2 * (13.287712379549449f / 64.0f));
  float ang = (float)pos[s] * invf;
  float2 cs; cs.x = cosf(ang); cs.y = sinf(ang);
  tab[idx] = cs;
}

// ---------------------------------------------------------------------------
// K-only RoPE (table-driven): 1/5 of the old rope kernel's work. Q-rope is
// fused into the attn Q-load (lane-local there).
// [R11 lesson: fusing rope into the GEMM epilogue taxes the GEMM's
//  VGPR/occupancy budget (total 370 vs 343.7) -- rope belongs here/in attn.]
// ---------------------------------------------------------------------------
__global__ void rope_k_kernel(ushort* __restrict__ kb, const float2* __restrict__ tab) {
  int idx = blockIdx.x * 256 + threadIdx.x;
  const int total = S * KVH * 64;
  if (idx >= total) return;
  int j = idx & 63;
  int t = idx >> 6;
  int kvh_i = t & 3;                        // KVH = 4
  int srow  = t >> 2;
  ushort* base = kb + (size_t)srow * (KVH * HD) + kvh_i * HD;
  float2 cs = tab[(size_t)srow * 64 + j];
  float x1 = bf2f(base[j]), x2 = bf2f(base[j + 64]);
  base[j]      = f2bf(x1 * cs.x - x2 * cs.y);
  base[j + 64] = f2bf(x2 * cs.x + x1 * cs.y);
}

// ---------------------------------------------------------------------------
// bf16 MFMA GEMM tile (NT), m97 recipe — SINGLE-buffered (R3/R0 form; R7
// proved explicit dbuf regresses this structure, matching learn_hip m99/m100).
// EXACT R9 form. OUT_MODE: 0 fp32, 1 bf16, 2 bf16 transposed.
// ---------------------------------------------------------------------------
template <int OUT_MODE>
__device__ __forceinline__ void gemm_tile(const ushort* __restrict__ A,
                                          const ushort* __restrict__ Bt,
                                          void* __restrict__ Cv,
                                          int M, int N, int K, int bxi, int byi,
                                          ushort* As, ushort* Bs) {
  const int bm = byi * 128;
  const int bn = bxi * 128;
  const int tid  = threadIdx.x;
  const int lane = tid & 63;
  const int w    = tid >> 6;
  const int wr = w >> 1, wc = w & 1;
  const int lm = lane & 15, quad = lane >> 4;

  f32x4 acc[4][4];
#pragma unroll
  for (int i = 0; i < 4; ++i)
#pragma unroll
    for (int j = 0; j < 4; ++j) acc[i][j] = (f32x4){0.f, 0.f, 0.f, 0.f};

  for (int k0 = 0; k0 < K; k0 += 32) {
#pragma unroll
    for (int j = 0; j < 2; ++j) {
      int idx = j * 256 + tid;
      int row = idx >> 2;
      int col = (idx & 3) * 8;
      int ubase = (j * 256 + w * 64) * 8;
      async_copy16(A + (size_t)(bm + row) * K + k0 + col, &As[ubase]);
      async_copy16(Bt + (size_t)(bn + row) * K + k0 + col, &Bs[ubase]);
    }
    __syncthreads();
    short8 af[4], bfr[4];
#pragma unroll
    for (int t = 0; t < 4; ++t) {
      af[t]  = *(const short8*)&As[(wr * 64 + t * 16 + lm) * 32 + quad * 8];
      bfr[t] = *(const short8*)&Bs[(wc * 64 + t * 16 + lm) * 32 + quad * 8];
    }
#pragma unroll
    for (int i = 0; i < 4; ++i)
#pragma unroll
      for (int j = 0; j < 4; ++j)
        acc[i][j] = __builtin_amdgcn_mfma_f32_16x16x32_bf16(af[i], bfr[j], acc[i][j], 0, 0, 0);
    __syncthreads();
  }

#pragma unroll
  for (int i = 0; i < 4; ++i)
#pragma unroll
    for (int j = 0; j < 4; ++j) {
      if (OUT_MODE == 2) {
        int col  = bn + wc * 64 + j * 16 + lm;
        int rowb = bm + wr * 64 + i * 16 + quad * 4;
        ushort4 o4;
        o4.x = f2bf(acc[i][j][0]); o4.y = f2bf(acc[i][j][1]);
        o4.z = f2bf(acc[i][j][2]); o4.w = f2bf(acc[i][j][3]);
        *(ushort4*)&((ushort*)Cv)[(size_t)col * M + rowb] = o4;
      } else {
#pragma unroll
        for (int r = 0; r < 4; ++r) {
          size_t row = bm + wr * 64 + i * 16 + quad * 4 + r;
          size_t col = bn + wc * 64 + j * 16 + lm;
          if (OUT_MODE == 1) ((ushort*)Cv)[row * N + col] = f2bf(acc[i][j][r]);
          else               ((float*)Cv)[row * N + col]  = acc[i][j][r];
        }
      }
    }
}

__global__ __launch_bounds__(256) void gemm_qkv_kernel(const ushort* __restrict__ hb,
                                                       const ushort* __restrict__ wq,
                                                       const ushort* __restrict__ wk,
                                                       const ushort* __restrict__ wv,
                                                       ushort* __restrict__ qb,
                                                       ushort* __restrict__ kb,
                                                       ushort* __restrict__ vtb) {
  __shared__ __align__(16) ushort As[128 * 32];
  __shared__ __align__(16) ushort Bs[128 * 32];
  int bid = blockIdx.x;
  if (bid < 512) {
    gemm_tile<1>(hb, wq, qb, S, H * HD, D, bid & 15, bid >> 4, As, Bs);
  } else if (bid < 640) {
    int b = bid - 512;
    gemm_tile<1>(hb, wk, kb, S, KVH * HD, D, b & 3, b >> 2, As, Bs);
  } else {
    int b = bid - 640;
    gemm_tile<2>(hb, wv, vtb, S, KVH * HD, D, b & 3, b >> 2, As, Bs);
  }
}

template <int OUT_MODE>
__global__ __launch_bounds__(256) void gemm_bt_kernel(const ushort* __restrict__ A,
                                                      const ushort* __restrict__ Bt,
                                                      void* __restrict__ Cv,
                                                      int M, int N, int K) {
  __shared__ __align__(16) ushort As[128 * 32];
  __shared__ __align__(16) ushort Bs[128 * 32];
  gemm_tile<OUT_MODE>(A, Bt, Cv, M, N, K, blockIdx.x, blockIdx.y, As, Bs);
}

// ---------------------------------------------------------------------------
// Transposed-flow bf16 MFMA causal flash attention (32x32x16), frag-major LDS.
// R9 attn kernel (114.6 us best-measured) + fused Q-RoPE at Q-load:
// the pair (d, d+64) is (qf[s], qf[s+4]) at the same lane/j -> LANE-LOCAL
// rotation, once per block, before the main loop (min register pressure).
// cos/sin from the precomputed table (contiguous 64B reads, L2-resident).
//  - kvh-per-XCD pinning (R3: FETCH 30.7 -> 16.4 MB)
//  - P lane^32 exchange via v_permlane32_swap (R7: -4.6 us vs ds_bpermute)
// [R6 lesson: V must stay LDS-staged; direct global V-frags = 64-line scatter.]
// Block = 512 thr = 8 waves = 4 q-groups x 2 kv-parities; q-tile 128; kv 64.
// Grid 512, descending qi; XCD = bid%8, h = 2*(bid&7)+((bid>>3)&1).
// ---------------------------------------------------------------------------
__global__ __launch_bounds__(512) void attn_mfma_kernel(const ushort* __restrict__ q,
                                                        const ushort* __restrict__ k,
                                                        const ushort* __restrict__ Vt,
                                                        ushort* __restrict__ o,
                                                        const float2* __restrict__ tab) {
  const int bid = blockIdx.x;
  const int h   = 2 * (bid & 7) + ((bid >> 3) & 1);   // kvh = h>>2 constant per XCD
  const int t   = bid >> 4;                 // 0..31
  const int qi  = 31 - t;                   // descending work order
  const int q0  = qi * 128;
  const int kvh = h >> 2;
  const int tid  = threadIdx.x;
  const int lane = tid & 63;
  const int w    = tid >> 6;                // 0..7
  const int qw   = w >> 1;                  // q-group 0..3
  const int ks   = w & 1;                   // kv parity 0..1
  const int m32  = lane & 31;
  const int p    = lane >> 5;

  // [buf][K: 16 chunks x 512] at 0 / [buf][V: 16 chunks x 512] at 16384
  __shared__ __align__(16) ushort LDSu[32768];

  const int q0w = q0 + qw * 32;

  // Q B-frags: B[n=q=lane&31][d=16s+8p+j]
  short8 qf[8];
#pragma unroll
  for (int s = 0; s < 8; ++s)
    qf[s] = *(const short8*)&q[(size_t)(q0w + m32) * (H * HD) + h * HD + s * 16 + p * 8];

  // ---- fused Q-RoPE (lane-local): d = s*16 + p*8 + j; pair at qf[s]/qf[s+4]
  {
    const float2* trow = tab + (size_t)(q0w + m32) * 64 + p * 8;
#pragma unroll
    for (int s = 0; s < 4; ++s) {
#pragma unroll
      for (int j = 0; j < 8; ++j) {
        float2 cs = trow[s * 16 + j];
        float lo = bf2f((ushort)qf[s][j]);
        float hi = bf2f((ushort)qf[s + 4][j]);
        qf[s][j]     = (short)f2bf(lo * cs.x - hi * cs.y);
        qf[s + 4][j] = (short)f2bf(hi * cs.x + lo * cs.y);
      }
    }
  }

  f32x16 Oacc[4];
#pragma unroll
  for (int i = 0; i < 4; ++i)
#pragma unroll
    for (int r = 0; r < 16; ++r) Oacc[i][r] = 0.f;
  float ls4[4] = {0.f, 0.f, 0.f, 0.f};      // 4 independent lsum chains

  // wave w stages chunks [4w, 4w+4): waves 0-3 -> K, waves 4-7 -> V
  auto stage = [&](int k0s, int buf) {
#pragma unroll
    for (int i = 0; i < 4; ++i) {
      int c = w * 4 + i;
      if (c < 16) {
        int kh = c >> 3, s = c & 7;
        async_copy16(&k[(size_t)(k0s + kh * 32 + m32) * (KVH * HD) + kvh * HD + s * 16 + p * 8],
                     &LDSu[buf * 8192 + c * 512]);
      } else {
        int cv = c - 16;
        int ht = cv >> 2, t2 = cv & 3;
        async_copy16(&Vt[(size_t)(kvh * HD + ht * 32 + m32) * S + k0s + t2 * 16 + p * 8],
                     &LDSu[16384 + buf * 8192 + cv * 512]);
      }
    }
  };

  stage(0, 0);
  __syncthreads();

  const float C1  = 0.08838834764831845f * 1.4426950408889634f;  // scale*log2e
  const float F2n = -12.0f * 1.4426950408889634f;                // -FM*log2e
  const int T = 2 * qi + 2;

  for (int tt = 0; tt < T; ++tt) {
    const int k0  = tt * 64;
    const int cur = tt & 1;
    if (tt + 1 < T) stage(k0 + 64, cur ^ 1);
    const ushort* Kb = &LDSu[cur * 8192];
    const ushort* Vb = &LDSu[16384 + cur * 8192];

    const int kbase = k0 + ks * 32;          // this wave's kv-subtile
    if (kbase <= q0w + 31) {                 // wave-uniform subtile liveness
      // ---- S^T subtile: 8 MFMA, two independent chains ----
      f32x16 stA, stB;
#pragma unroll
      for (int r = 0; r < 16; ++r) { stA[r] = 0.f; stB[r] = 0.f; }
#pragma unroll
      for (int s = 0; s < 8; s += 2) {
        short8 kf0 = *(const short8*)&Kb[(ks * 8 + s) * 512 + lane * 8];
        short8 kf1 = *(const short8*)&Kb[(ks * 8 + s + 1) * 512 + lane * 8];
        stA = __builtin_amdgcn_mfma_f32_32x32x16_bf16(kf0, qf[s], stA, 0, 0, 0);
        stB = __builtin_amdgcn_mfma_f32_32x32x16_bf16(kf1, qf[s + 1], stB, 0, 0, 0);
      }

      // ---- softmax terms ----
      float pv[16];
      if (kbase == q0w) {                    // diagonal subtile: masked path
#pragma unroll
        for (int r = 0; r < 16; ++r) {
          int kvl = (r & 3) + 8 * (r >> 2) + 4 * p;
          float e = fast_exp2(fmaf(stA[r] + stB[r], C1, F2n));
          e = (kvl > m32) ? 0.f : e;
          pv[r] = e; ls4[r & 3] += e;
        }
      } else {                               // clean subtile: no compares
#pragma unroll
        for (int r = 0; r < 16; ++r) {
          float e = fast_exp2(fmaf(stA[r] + stB[r], C1, F2n));
          pv[r] = e; ls4[r & 3] += e;
        }
      }

      // ---- C-layout -> PV B-frag: pack + permlane32_swap (VALU, no DS) ----
      unsigned own2[4][2];
#pragma unroll
      for (int g = 0; g < 4; ++g) {
        own2[g][0] = pkbf_t(pv[4 * g + 0], pv[4 * g + 1]);
        own2[g][1] = pkbf_t(pv[4 * g + 2], pv[4 * g + 3]);
      }
      short8 pf[2];
#pragma unroll
      for (int t2 = 0; t2 < 2; ++t2) {
        unsigned x0, y0, x1, y1;
        swap_half(own2[2 * t2][0], own2[2 * t2 + 1][0], x0, y0);
        swap_half(own2[2 * t2][1], own2[2 * t2 + 1][1], x1, y1);
        union { unsigned u4[4]; short8 s8; } pb;
        pb.u4[0] = x0; pb.u4[1] = x1; pb.u4[2] = y0; pb.u4[3] = y1;
        pf[t2] = pb.s8;
      }

      // ---- O^T += V^T·P : 8 MFMA (4 independent ht chains) ----
#pragma unroll
      for (int ht = 0; ht < 4; ++ht)
#pragma unroll
        for (int t2l = 0; t2l < 2; ++t2l) {
          int cv = ht * 4 + ks * 2 + t2l;
          short8 vf = *(const short8*)&Vb[cv * 512 + lane * 8];
          Oacc[ht] = __builtin_amdgcn_mfma_f32_32x32x16_bf16(vf, pf[t2l], Oacc[ht], 0, 0, 0);
        }
    }
    __syncthreads();
  }

  // ---- epilogue: merge kv-parity partners through LDS, then store ----
  float lsum = (ls4[0] + ls4[1]) + (ls4[2] + ls4[3]);
  float* mb = (float*)LDSu;                  // 16384 floats, loop is done with LDS

  // phase 1: lsum exchange (ks=1 -> ks=0)
  if (ks) mb[(qw << 6) | lane] = lsum;
  __syncthreads();
  if (!ks) lsum += mb[(qw << 6) | lane];
  __syncthreads();

  // phase 2: Oacc exchange, conflict-free [r][lane] layout (stride 4B)
  if (ks) {
    float* base = mb + qw * 4096;
#pragma unroll
    for (int ht = 0; ht < 4; ++ht)
#pragma unroll
      for (int r = 0; r < 16; ++r)
        base[ht * 1024 + r * 64 + lane] = Oacc[ht][r];
  }
  __syncthreads();

  if (!ks) {
    const float* base = mb + qw * 4096;
#pragma unroll
    for (int ht = 0; ht < 4; ++ht)
#pragma unroll
      for (int r = 0; r < 16; ++r)
        Oacc[ht][r] += base[ht * 1024 + r * 64 + lane];

    float ltot = lsum + __shfl_xor(lsum, 32);
    float inv = 1.0f / ltot;
#pragma unroll
    for (int ht = 0; ht < 4; ++ht)
#pragma unroll
      for (int rq = 0; rq < 4; ++rq) {
        uint2 dd;
        dd.x = pkbf(Oacc[ht][4 * rq + 0] * inv, Oacc[ht][4 * rq + 1] * inv);
        dd.y = pkbf(Oacc[ht][4 * rq + 2] * inv, Oacc[ht][4 * rq + 3] * inv);
        *(uint2*)&o[(size_t)(q0w + m32) * (H * HD) + h * HD + ht * 32 + 8 * rq + 4 * p] = dd;
      }
  }
}

// ---------------------------------------------------------------------------
// cvt(1) -> trig table(1) -> QKV proj(1) -> K-rope(1) -> flash attn + Q-rope(1)
// -> O proj(1)
// ---------------------------------------------------------------------------
extern "C" void kernel_launch(void* const* d_in, const int* in_sizes, int n_in,
                              void* d_out, int out_size, void* d_ws, size_t ws_size,
                              hipStream_t stream) {
  const float* hidden = (const float*)d_in[0];
  const float* Wq     = (const float*)d_in[1];
  const float* Wk     = (const float*)d_in[2];
  const float* Wv     = (const float*)d_in[3];
  const float* Wo     = (const float*)d_in[4];
  const int*   pos    = (const int*)d_in[5];
  float* out = (float*)d_out;

  ushort* hb  = (ushort*)d_ws;
  ushort* wqb = hb  + N_HID;
  ushort* wkb = wqb + N_WQ;
  ushort* wvb = wkb + N_WKV;
  ushort* wob = wvb + N_WKV;
  ushort* qb  = wob + N_WQ;
  ushort* kb  = qb  + (size_t)S * (H * HD);
  ushort* vtb = kb  + (size_t)S * (KVH * HD);
  ushort* ob  = vtb + (size_t)(KVH * HD) * S;
  float2* tab = (float2*)(ob + (size_t)S * (H * HD));   // 2MB (ws headroom proven in R5)

  dim3 blk(256);
  size_t n4 = C5_ / 4;
  cvt_all_kernel<<<(int)((n4 + 255) / 256), blk, 0, stream>>>(hidden, Wq, Wk, Wv, Wo, hb);

  trig_table_kernel<<<(S * 64 + 255) / 256, blk, 0, stream>>>(pos, tab);

  gemm_qkv_kernel<<<dim3(768), blk, 0, stream>>>(hb, wqb, wkb, wvb, qb, kb, vtb);

  rope_k_kernel<<<(S * KVH * 64 + 255) / 256, blk, 0, stream>>>(kb, tab);

  attn_mfma_kernel<<<dim3(512), dim3(512), 0, stream>>>(qb, kb, vtb, ob, tab);

  gemm_bt_kernel<0><<<dim3(D / 128, S / 128), blk, 0, stream>>>(ob, wob, out, S, D, D);
}